// Round 2
// baseline (1291.707 us; speedup 1.0000x reference)
//
#include <hip/hip_runtime.h>

// VQ-VAE quantize: input (16,64,64,64) f32, embeddings (64,2048) f32.
// Outputs concat in d_out: quantize_st[4194304], loss[1], embed_ind[65536] (as float).
//
// Correctness-critical (PASSED round 1, absmax 0.0 — do not change arithmetic):
//   dist = fl( fl(sx - 2*dot) + se ),  dot = sequential-k FMA chain (k=0..63),
//   sx = numpy pairwise (8 accumulators + tree), se = sequential axis-0 sum,
//   argmin = first index of minimum (strict <, ascending j 0..2047).
//
// Round-2 structural change: j is a block-uniform loop counter (all lanes scan
// all 2048 codes; lanes = pixels). Uniform ET addresses -> scalar s_load path,
// inner loop = pure v_fmac_f32 with SGPR e-operand. 1-wave blocks.

#define HW     4096      // 64*64
#define CHW    262144    // 64*4096
#define NE     2048
#define OUT_Q  4194304   // NPIX*DIM
#define WS_ET  0         // ET[j][k]: 2048*64 floats
#define WS_SE  131072    // se[j]: 2048 floats
#define WS_ACC 133120    // loss accumulator: 1 float

__global__ __launch_bounds__(256) void vq_prep(const float* __restrict__ emb,
                                               float* __restrict__ ws) {
  int bid = blockIdx.x;
  if (bid < 512) {
    // transpose: ET[j*64+k] = emb[k*2048+j]; t = k*2048+j (coalesced read)
    int t = bid * 256 + threadIdx.x;
    int k = t >> 11;
    int j = t & 2047;
    ws[WS_ET + j * 64 + k] = emb[t];
  } else {
    // se[j] = sum_k fl(e_kj^2), sequential over k (numpy axis-0 reduce order)
    int j = (bid - 512) * 256 + threadIdx.x;
    float s = 0.0f;
    for (int k = 0; k < 64; ++k) {
      float e = emb[k * NE + j];
      s = __fadd_rn(s, __fmul_rn(e, e));
    }
    ws[WS_SE + j] = s;
    if (j == 0) ws[WS_ACC] = 0.0f;
  }
}

__global__ __launch_bounds__(64, 4) void vq_main(const float* __restrict__ inp,
                                                 const float* __restrict__ et,
                                                 const float* __restrict__ se,
                                                 float* __restrict__ out,
                                                 float* __restrict__ loss_acc) {
  const int lane = threadIdx.x;                 // 64 lanes = 64 pixels
  const int n    = blockIdx.x * 64 + lane;      // pixel id in (B,H,W) flat order
  const int b    = n >> 12;
  const int rem  = n & 4095;                    // h*64+w (block never straddles b)
  const float* xp = inp + (size_t)b * CHW + rem;

  // x[c] in registers, statically indexed only (rule #20)
  float x[64];
#pragma unroll
  for (int c = 0; c < 64; ++c) x[c] = xp[c * HW];

  // sx: numpy pairwise sum of squares (8 accumulators over 8 chunks, then tree)
  float r[8];
#pragma unroll
  for (int i = 0; i < 8; ++i) r[i] = __fmul_rn(x[i], x[i]);
#pragma unroll
  for (int blk = 1; blk < 8; ++blk) {
#pragma unroll
    for (int i = 0; i < 8; ++i)
      r[i] = __fadd_rn(r[i], __fmul_rn(x[blk * 8 + i], x[blk * 8 + i]));
  }
  const float sx =
      __fadd_rn(__fadd_rn(__fadd_rn(r[0], r[1]), __fadd_rn(r[2], r[3])),
                __fadd_rn(__fadd_rn(r[4], r[5]), __fadd_rn(r[6], r[7])));

  float best = 3.402823466e38f;
  int   bi   = 0;

  // j loop: BLOCK-UNIFORM counter -> et/se addresses uniform -> scalar loads.
  // Manual x2 unroll: two independent FMA chains (each bit-identical to the
  // sequential-k chain for its own j).
  for (int j = 0; j < NE; j += 2) {
    const float4* e0 = reinterpret_cast<const float4*>(et + j * 64);
    const float4* e1 = reinterpret_cast<const float4*>(et + j * 64 + 64);
    float dot0 = 0.0f, dot1 = 0.0f;
#pragma unroll
    for (int kk = 0; kk < 16; ++kk) {
      float4 a = e0[kk];
      float4 c = e1[kk];
      dot0 = __fmaf_rn(x[4 * kk + 0], a.x, dot0);
      dot1 = __fmaf_rn(x[4 * kk + 0], c.x, dot1);
      dot0 = __fmaf_rn(x[4 * kk + 1], a.y, dot0);
      dot1 = __fmaf_rn(x[4 * kk + 1], c.y, dot1);
      dot0 = __fmaf_rn(x[4 * kk + 2], a.z, dot0);
      dot1 = __fmaf_rn(x[4 * kk + 2], c.z, dot1);
      dot0 = __fmaf_rn(x[4 * kk + 3], a.w, dot0);
      dot1 = __fmaf_rn(x[4 * kk + 3], c.w, dot1);
    }
    float dist0 = __fadd_rn(__fsub_rn(sx, __fmul_rn(2.0f, dot0)), se[j]);
    float dist1 = __fadd_rn(__fsub_rn(sx, __fmul_rn(2.0f, dot1)), se[j + 1]);
    if (dist0 < best) { best = dist0; bi = j; }       // strict <: first index wins
    if (dist1 < best) { best = dist1; bi = j + 1; }
  }

  // epilogue: gather code row (contiguous in ET), write quantize_st + ind
  const float4* qrow = reinterpret_cast<const float4*>(et + bi * 64);
  float lsum = 0.0f;
  float* op = out + (size_t)b * CHW + rem;
#pragma unroll
  for (int kk = 0; kk < 16; ++kk) {
    float4 q4 = qrow[kk];                         // per-lane gather, L2-hot
    float qv[4] = {q4.x, q4.y, q4.z, q4.w};
#pragma unroll
    for (int i = 0; i < 4; ++i) {
      int c = 4 * kk + i;
      float d = __fsub_rn(qv[i], x[c]);
      op[c * HW] = __fadd_rn(x[c], d);            // x + (q - x)
      lsum = __fadd_rn(lsum, __fmul_rn(d, d));
    }
  }
  out[OUT_Q + 1 + n] = (float)bi;

  // wave-level loss reduce, one atomic per block (1024 blocks total)
#pragma unroll
  for (int off = 32; off > 0; off >>= 1)
    lsum = __fadd_rn(lsum, __shfl_xor(lsum, off, 64));
  if (lane == 0) atomicAdd(loss_acc, lsum);
}

__global__ void vq_final(const float* __restrict__ ws, float* __restrict__ out) {
  float m = ws[WS_ACC] / 4194304.0f;              // exact pow2 divide
  out[OUT_Q] = __fadd_rn(m, __fmul_rn(0.25f, m)); // mean + 0.25*mean
}

extern "C" void kernel_launch(void* const* d_in, const int* in_sizes, int n_in,
                              void* d_out, int out_size, void* d_ws, size_t ws_size,
                              hipStream_t stream) {
  const float* inp = (const float*)d_in[0];
  const float* emb = (const float*)d_in[1];
  float* out = (float*)d_out;
  float* ws  = (float*)d_ws;

  vq_prep<<<520, 256, 0, stream>>>(emb, ws);
  vq_main<<<1024, 64, 0, stream>>>(inp, ws + WS_ET, ws + WS_SE, out, ws + WS_ACC);
  vq_final<<<1, 1, 0, stream>>>(ws, out);
}

// Round 4
// 335.348 us; speedup vs baseline: 3.8518x; 3.8518x over previous
//
#include <hip/hip_runtime.h>

// VQ-VAE quantize: input (16,64,64,64) f32, embeddings (64,2048) f32.
// Outputs concat in d_out: quantize_st[4194304], loss[1], embed_ind[65536] (as float).
//
// Correctness-critical (absmax 0.0 in rounds 1-2 — do not change arithmetic):
//   dist = fl( fl(sx - 2*dot) + se ),  dot = sequential-k FMA chain (k=0..63),
//   sx = numpy pairwise (8 accumulators + tree), se = sequential axis-0 sum,
//   argmin = first index of minimum (strict <, ascending j; wave slices ascending).
//
// Structure (round 3, resubmitted after infra flake): 8 waves/block, wave w owns
// codes [w*256, w*256+256). Codes staged in 8-code chunks through WAVE-PRIVATE
// LDS (no barriers in main loop); all lanes read the same LDS address -> HW
// broadcast, conflict-free. x held in 16 named float4 registers (rounds 1/2
// bug: compiler demoted x[64] to per-j reloads — VGPR_Count was 48).

#define HW     4096      // 64*64
#define CHW    262144    // 64*4096
#define NE     2048
#define OUT_Q  4194304   // NPIX*DIM
#define WS_ET  0         // ET[j][k]: 2048*64 floats
#define WS_SE  131072    // se[j]: 2048 floats
#define WS_ACC 133120    // loss accumulator: 1 float

__global__ __launch_bounds__(256) void vq_prep(const float* __restrict__ emb,
                                               float* __restrict__ ws) {
  int bid = blockIdx.x;
  if (bid < 512) {
    // transpose: ET[j*64+k] = emb[k*2048+j]; t = k*2048+j (coalesced read)
    int t = bid * 256 + threadIdx.x;
    int k = t >> 11;
    int j = t & 2047;
    ws[WS_ET + j * 64 + k] = emb[t];
  } else {
    // se[j] = sum_k fl(e_kj^2), sequential over k
    int j = (bid - 512) * 256 + threadIdx.x;
    float s = 0.0f;
    for (int k = 0; k < 64; ++k) {
      float e = emb[k * NE + j];
      s = __fadd_rn(s, __fmul_rn(e, e));
    }
    ws[WS_SE + j] = s;
    if (j == 0) ws[WS_ACC] = 0.0f;
  }
}

#define SQ(v) __fmul_rn(v, v)
#define LDX(k) make_float4(xp[(4*k+0)*HW], xp[(4*k+1)*HW], xp[(4*k+2)*HW], xp[(4*k+3)*HW])
// two interleaved sequential-k FMA chains (independent ILP, per-chain order
// identical to rounds 1-2: k ascending, components x,y,z,w)
#define DOTK(k) { \
  float4 ea = e0[k], eb = e1[k]; \
  d0 = __fmaf_rn(x##k.x, ea.x, d0); d1 = __fmaf_rn(x##k.x, eb.x, d1); \
  d0 = __fmaf_rn(x##k.y, ea.y, d0); d1 = __fmaf_rn(x##k.y, eb.y, d1); \
  d0 = __fmaf_rn(x##k.z, ea.z, d0); d1 = __fmaf_rn(x##k.z, eb.z, d1); \
  d0 = __fmaf_rn(x##k.w, ea.w, d0); d1 = __fmaf_rn(x##k.w, eb.w, d1); }
#define DOTALL() \
  DOTK(0) DOTK(1) DOTK(2) DOTK(3) DOTK(4) DOTK(5) DOTK(6) DOTK(7) \
  DOTK(8) DOTK(9) DOTK(10) DOTK(11) DOTK(12) DOTK(13) DOTK(14) DOTK(15)
#define SXB(e, o) \
  r0 = __fadd_rn(r0, SQ(e.x)); r1 = __fadd_rn(r1, SQ(e.y)); \
  r2 = __fadd_rn(r2, SQ(e.z)); r3 = __fadd_rn(r3, SQ(e.w)); \
  r4 = __fadd_rn(r4, SQ(o.x)); r5 = __fadd_rn(r5, SQ(o.y)); \
  r6 = __fadd_rn(r6, SQ(o.z)); r7 = __fadd_rn(r7, SQ(o.w));
// process the 8-code chunk currently in this wave's LDS buffer
#define CHUNK_BODY(jb_) { \
  const int jb = (jb_); \
  _Pragma("unroll") \
  for (int jl = 0; jl < 8; jl += 2) { \
    const float4* e0 = reinterpret_cast<const float4*>(&lds_e[wv][jl][0]); \
    const float4* e1 = reinterpret_cast<const float4*>(&lds_e[wv][jl + 1][0]); \
    float d0 = 0.0f, d1 = 0.0f; \
    DOTALL() \
    int j = jb + jl; \
    float dist0 = __fadd_rn(__fsub_rn(sx, __fmul_rn(2.0f, d0)), se[j]); \
    float dist1 = __fadd_rn(__fsub_rn(sx, __fmul_rn(2.0f, d1)), se[j + 1]); \
    if (dist0 < best) { best = dist0; bi = j; } \
    if (dist1 < best) { best = dist1; bi = j + 1; } \
  } }

__global__ __launch_bounds__(512, 4) void vq_main(const float* __restrict__ inp,
                                                  const float* __restrict__ et,
                                                  const float* __restrict__ se,
                                                  float* __restrict__ out,
                                                  float* __restrict__ loss_acc) {
  __shared__ float lds_e[8][8][64];   // 16 KB: per-wave 8-code chunk buffer
  __shared__ float rv[8][64];
  __shared__ int   ri[8][64];
  __shared__ float ls[8];

  const int tid  = threadIdx.x;
  const int lane = tid & 63;
  const int wv   = tid >> 6;                    // wave id = code-slice 0..7
  const int n    = blockIdx.x * 64 + lane;      // pixel id (same set for all waves)
  const int b    = n >> 12;
  const int rem  = n & 4095;                    // block never straddles b
  const float* xp = inp + (size_t)b * CHW + rem;

  // x in 16 named float4 registers (statically indexed only)
  float4 x0 = LDX(0),  x1 = LDX(1),  x2 = LDX(2),  x3 = LDX(3);
  float4 x4 = LDX(4),  x5 = LDX(5),  x6 = LDX(6),  x7 = LDX(7);
  float4 x8 = LDX(8),  x9 = LDX(9),  x10 = LDX(10), x11 = LDX(11);
  float4 x12 = LDX(12), x13 = LDX(13), x14 = LDX(14), x15 = LDX(15);

  // sx: numpy pairwise (8 accumulators over 8-element chunks, then tree)
  float r0 = SQ(x0.x), r1 = SQ(x0.y), r2 = SQ(x0.z), r3 = SQ(x0.w);
  float r4 = SQ(x1.x), r5 = SQ(x1.y), r6 = SQ(x1.z), r7 = SQ(x1.w);
  SXB(x2, x3) SXB(x4, x5) SXB(x6, x7) SXB(x8, x9)
  SXB(x10, x11) SXB(x12, x13) SXB(x14, x15)
  const float sx =
      __fadd_rn(__fadd_rn(__fadd_rn(r0, r1), __fadd_rn(r2, r3)),
                __fadd_rn(__fadd_rn(r4, r5), __fadd_rn(r6, r7)));

  // wave-private staging: slice base for this wave (256 codes = 64 KB)
  const float4* ET4 = reinterpret_cast<const float4*>(et + wv * 256 * 64);
  float4* L4 = reinterpret_cast<float4*>(&lds_e[wv][0][0]);
  const int j0 = wv * 256;

  float best = 3.402823466e38f;
  int   bi   = 0;

  // prefetch chunk 0 into registers
  float4 p0 = ET4[lane], p1 = ET4[lane + 64];

#pragma unroll 1
  for (int c = 0; c < 31; ++c) {                // chunks 0..30 (8 codes each)
    // issue next-chunk loads early (T14): latency hides under this chunk's FMAs
    const float4* src = ET4 + (c + 1) * 128;
    float4 n0 = src[lane], n1 = src[lane + 64];

    // write current chunk to wave-private LDS (DS in-order: reads below see it)
    L4[lane] = p0;
    L4[lane + 64] = p1;

    CHUNK_BODY(j0 + c * 8)
    p0 = n0; p1 = n1;
  }
  // final chunk 31 (no prefetch)
  L4[lane] = p0;
  L4[lane + 64] = p1;
  CHUNK_BODY(j0 + 31 * 8)

  rv[wv][lane] = best;
  ri[wv][lane] = bi;
  __syncthreads();

  // merge across 8 waves (slices ascending in j -> strict < keeps lowest j)
  float bv  = rv[0][lane];
  int   bix = ri[0][lane];
#pragma unroll
  for (int s = 1; s < 8; ++s) {
    float v = rv[s][lane];
    if (v < bv) { bv = v; bix = ri[s][lane]; }
  }

  // epilogue: pixel = lane, wave wv writes channels [wv*8, wv*8+8)
  const float4* qr = reinterpret_cast<const float4*>(et + (size_t)bix * 64);
  float4 qa = qr[2 * wv], qb = qr[2 * wv + 1];
  float q[8] = {qa.x, qa.y, qa.z, qa.w, qb.x, qb.y, qb.z, qb.w};
  float* op = out + (size_t)b * CHW + rem;
  float lsum = 0.0f;
#pragma unroll
  for (int i = 0; i < 8; ++i) {
    int c = wv * 8 + i;
    float xv = xp[c * HW];                 // L1-hot re-read (avoids dynamic x-reg index)
    float d  = __fsub_rn(q[i], xv);
    op[c * HW] = __fadd_rn(xv, d);         // x + (q - x)
    lsum = __fadd_rn(lsum, __fmul_rn(d, d));
  }
  if (wv == 0) out[OUT_Q + 1 + n] = (float)bix;

  // loss: wave shfl reduce -> per-wave slot -> one atomic per block
#pragma unroll
  for (int off = 32; off > 0; off >>= 1)
    lsum = __fadd_rn(lsum, __shfl_xor(lsum, off, 64));
  if (lane == 0) ls[wv] = lsum;
  __syncthreads();
  if (tid == 0) {
    float s = ls[0];
#pragma unroll
    for (int w = 1; w < 8; ++w) s = __fadd_rn(s, ls[w]);
    atomicAdd(loss_acc, s);
  }
}

__global__ void vq_final(const float* __restrict__ ws, float* __restrict__ out) {
  float m = ws[WS_ACC] / 4194304.0f;              // exact pow2 divide
  out[OUT_Q] = __fadd_rn(m, __fmul_rn(0.25f, m)); // mean + 0.25*mean
}

extern "C" void kernel_launch(void* const* d_in, const int* in_sizes, int n_in,
                              void* d_out, int out_size, void* d_ws, size_t ws_size,
                              hipStream_t stream) {
  const float* inp = (const float*)d_in[0];
  const float* emb = (const float*)d_in[1];
  float* out = (float*)d_out;
  float* ws  = (float*)d_ws;

  vq_prep<<<520, 256, 0, stream>>>(emb, ws);
  vq_main<<<1024, 512, 0, stream>>>(inp, ws + WS_ET, ws + WS_SE, out, ws + WS_ACC);
  vq_final<<<1, 1, 0, stream>>>(ws, out);
}

// Round 5
// 332.137 us; speedup vs baseline: 3.8891x; 1.0097x over previous
//
#include <hip/hip_runtime.h>

// VQ-VAE quantize: input (16,64,64,64) f32, embeddings (64,2048) f32.
// Outputs concat in d_out: quantize_st[4194304], loss[1], embed_ind[65536] (as float).
//
// Correctness-critical (absmax 0.0 in rounds 1,2,4 — do not change arithmetic):
//   dist = fl( fl(sx - 2*dot) + se ),  dot = sequential-k FMA chain (k=0..63),
//   sx = numpy pairwise (8 accumulators + tree), se = sequential axis-0 sum,
//   argmin = first index of minimum (strict <, ascending j; wave slices ascending).
//
// Structure: 8 waves/block, wave w owns codes [w*256, w*256+256). Codes staged
// in 8-code chunks through WAVE-PRIVATE LDS (no barriers in main loop); all
// lanes read the same LDS address -> HW broadcast, conflict-free. x held in 16
// named float4 registers.
//
// Round-5 change: __launch_bounds__(512,4) had capped VGPR at 64 (the 32
// waves/CU budget), demoting x to reloads — 61% of VALU issue was non-FMA.
// (512,1) lifts the cap so x really lives in VGPRs (~110 expected, 4 waves/SIMD).

#define HW     4096      // 64*64
#define CHW    262144    // 64*4096
#define NE     2048
#define OUT_Q  4194304   // NPIX*DIM
#define WS_ET  0         // ET[j][k]: 2048*64 floats
#define WS_SE  131072    // se[j]: 2048 floats
#define WS_ACC 133120    // loss accumulator: 1 float

__global__ __launch_bounds__(256) void vq_prep(const float* __restrict__ emb,
                                               float* __restrict__ ws) {
  int bid = blockIdx.x;
  if (bid < 512) {
    // transpose: ET[j*64+k] = emb[k*2048+j]; t = k*2048+j (coalesced read)
    int t = bid * 256 + threadIdx.x;
    int k = t >> 11;
    int j = t & 2047;
    ws[WS_ET + j * 64 + k] = emb[t];
  } else {
    // se[j] = sum_k fl(e_kj^2), sequential over k
    int j = (bid - 512) * 256 + threadIdx.x;
    float s = 0.0f;
    for (int k = 0; k < 64; ++k) {
      float e = emb[k * NE + j];
      s = __fadd_rn(s, __fmul_rn(e, e));
    }
    ws[WS_SE + j] = s;
    if (j == 0) ws[WS_ACC] = 0.0f;
  }
}

#define SQ(v) __fmul_rn(v, v)
#define LDX(k) make_float4(xp[(4*k+0)*HW], xp[(4*k+1)*HW], xp[(4*k+2)*HW], xp[(4*k+3)*HW])
// two interleaved sequential-k FMA chains (independent ILP, per-chain order
// identical to rounds 1-2: k ascending, components x,y,z,w)
#define DOTK(k) { \
  float4 ea = e0[k], eb = e1[k]; \
  d0 = __fmaf_rn(x##k.x, ea.x, d0); d1 = __fmaf_rn(x##k.x, eb.x, d1); \
  d0 = __fmaf_rn(x##k.y, ea.y, d0); d1 = __fmaf_rn(x##k.y, eb.y, d1); \
  d0 = __fmaf_rn(x##k.z, ea.z, d0); d1 = __fmaf_rn(x##k.z, eb.z, d1); \
  d0 = __fmaf_rn(x##k.w, ea.w, d0); d1 = __fmaf_rn(x##k.w, eb.w, d1); }
#define DOTALL() \
  DOTK(0) DOTK(1) DOTK(2) DOTK(3) DOTK(4) DOTK(5) DOTK(6) DOTK(7) \
  DOTK(8) DOTK(9) DOTK(10) DOTK(11) DOTK(12) DOTK(13) DOTK(14) DOTK(15)
#define SXB(e, o) \
  r0 = __fadd_rn(r0, SQ(e.x)); r1 = __fadd_rn(r1, SQ(e.y)); \
  r2 = __fadd_rn(r2, SQ(e.z)); r3 = __fadd_rn(r3, SQ(e.w)); \
  r4 = __fadd_rn(r4, SQ(o.x)); r5 = __fadd_rn(r5, SQ(o.y)); \
  r6 = __fadd_rn(r6, SQ(o.z)); r7 = __fadd_rn(r7, SQ(o.w));
// process the 8-code chunk currently in this wave's LDS buffer
#define CHUNK_BODY(jb_) { \
  const int jb = (jb_); \
  _Pragma("unroll") \
  for (int jl = 0; jl < 8; jl += 2) { \
    const float4* e0 = reinterpret_cast<const float4*>(&lds_e[wv][jl][0]); \
    const float4* e1 = reinterpret_cast<const float4*>(&lds_e[wv][jl + 1][0]); \
    float d0 = 0.0f, d1 = 0.0f; \
    DOTALL() \
    int j = jb + jl; \
    float dist0 = __fadd_rn(__fsub_rn(sx, __fmul_rn(2.0f, d0)), se[j]); \
    float dist1 = __fadd_rn(__fsub_rn(sx, __fmul_rn(2.0f, d1)), se[j + 1]); \
    if (dist0 < best) { best = dist0; bi = j; } \
    if (dist1 < best) { best = dist1; bi = j + 1; } \
  } }

__global__ __launch_bounds__(512, 1) void vq_main(const float* __restrict__ inp,
                                                  const float* __restrict__ et,
                                                  const float* __restrict__ se,
                                                  float* __restrict__ out,
                                                  float* __restrict__ loss_acc) {
  __shared__ float lds_e[8][8][64];   // 16 KB: per-wave 8-code chunk buffer
  __shared__ float rv[8][64];
  __shared__ int   ri[8][64];
  __shared__ float ls[8];

  const int tid  = threadIdx.x;
  const int lane = tid & 63;
  const int wv   = tid >> 6;                    // wave id = code-slice 0..7
  const int n    = blockIdx.x * 64 + lane;      // pixel id (same set for all waves)
  const int b    = n >> 12;
  const int rem  = n & 4095;                    // block never straddles b
  const float* xp = inp + (size_t)b * CHW + rem;

  // x in 16 named float4 registers (statically indexed only)
  float4 x0 = LDX(0),  x1 = LDX(1),  x2 = LDX(2),  x3 = LDX(3);
  float4 x4 = LDX(4),  x5 = LDX(5),  x6 = LDX(6),  x7 = LDX(7);
  float4 x8 = LDX(8),  x9 = LDX(9),  x10 = LDX(10), x11 = LDX(11);
  float4 x12 = LDX(12), x13 = LDX(13), x14 = LDX(14), x15 = LDX(15);

  // sx: numpy pairwise (8 accumulators over 8-element chunks, then tree)
  float r0 = SQ(x0.x), r1 = SQ(x0.y), r2 = SQ(x0.z), r3 = SQ(x0.w);
  float r4 = SQ(x1.x), r5 = SQ(x1.y), r6 = SQ(x1.z), r7 = SQ(x1.w);
  SXB(x2, x3) SXB(x4, x5) SXB(x6, x7) SXB(x8, x9)
  SXB(x10, x11) SXB(x12, x13) SXB(x14, x15)
  const float sx =
      __fadd_rn(__fadd_rn(__fadd_rn(r0, r1), __fadd_rn(r2, r3)),
                __fadd_rn(__fadd_rn(r4, r5), __fadd_rn(r6, r7)));

  // wave-private staging: slice base for this wave (256 codes = 64 KB)
  const float4* ET4 = reinterpret_cast<const float4*>(et + wv * 256 * 64);
  float4* L4 = reinterpret_cast<float4*>(&lds_e[wv][0][0]);
  const int j0 = wv * 256;

  float best = 3.402823466e38f;
  int   bi   = 0;

  // prefetch chunk 0 into registers
  float4 p0 = ET4[lane], p1 = ET4[lane + 64];

#pragma unroll 1
  for (int c = 0; c < 31; ++c) {                // chunks 0..30 (8 codes each)
    // issue next-chunk loads early (T14): latency hides under this chunk's FMAs
    const float4* src = ET4 + (c + 1) * 128;
    float4 n0 = src[lane], n1 = src[lane + 64];

    // write current chunk to wave-private LDS (DS in-order: reads below see it)
    L4[lane] = p0;
    L4[lane + 64] = p1;

    CHUNK_BODY(j0 + c * 8)
    p0 = n0; p1 = n1;
  }
  // final chunk 31 (no prefetch)
  L4[lane] = p0;
  L4[lane + 64] = p1;
  CHUNK_BODY(j0 + 31 * 8)

  rv[wv][lane] = best;
  ri[wv][lane] = bi;
  __syncthreads();

  // merge across 8 waves (slices ascending in j -> strict < keeps lowest j)
  float bv  = rv[0][lane];
  int   bix = ri[0][lane];
#pragma unroll
  for (int s = 1; s < 8; ++s) {
    float v = rv[s][lane];
    if (v < bv) { bv = v; bix = ri[s][lane]; }
  }

  // epilogue: pixel = lane, wave wv writes channels [wv*8, wv*8+8)
  const float4* qr = reinterpret_cast<const float4*>(et + (size_t)bix * 64);
  float4 qa = qr[2 * wv], qb = qr[2 * wv + 1];
  float q[8] = {qa.x, qa.y, qa.z, qa.w, qb.x, qb.y, qb.z, qb.w};
  float* op = out + (size_t)b * CHW + rem;
  float lsum = 0.0f;
#pragma unroll
  for (int i = 0; i < 8; ++i) {
    int c = wv * 8 + i;
    float xv = xp[c * HW];                 // L1-hot re-read (avoids dynamic x-reg index)
    float d  = __fsub_rn(q[i], xv);
    op[c * HW] = __fadd_rn(xv, d);         // x + (q - x)
    lsum = __fadd_rn(lsum, __fmul_rn(d, d));
  }
  if (wv == 0) out[OUT_Q + 1 + n] = (float)bix;

  // loss: wave shfl reduce -> per-wave slot -> one atomic per block
#pragma unroll
  for (int off = 32; off > 0; off >>= 1)
    lsum = __fadd_rn(lsum, __shfl_xor(lsum, off, 64));
  if (lane == 0) ls[wv] = lsum;
  __syncthreads();
  if (tid == 0) {
    float s = ls[0];
#pragma unroll
    for (int w = 1; w < 8; ++w) s = __fadd_rn(s, ls[w]);
    atomicAdd(loss_acc, s);
  }
}

__global__ void vq_final(const float* __restrict__ ws, float* __restrict__ out) {
  float m = ws[WS_ACC] / 4194304.0f;              // exact pow2 divide
  out[OUT_Q] = __fadd_rn(m, __fmul_rn(0.25f, m)); // mean + 0.25*mean
}

extern "C" void kernel_launch(void* const* d_in, const int* in_sizes, int n_in,
                              void* d_out, int out_size, void* d_ws, size_t ws_size,
                              hipStream_t stream) {
  const float* inp = (const float*)d_in[0];
  const float* emb = (const float*)d_in[1];
  float* out = (float*)d_out;
  float* ws  = (float*)d_ws;

  vq_prep<<<520, 256, 0, stream>>>(emb, ws);
  vq_main<<<1024, 512, 0, stream>>>(inp, ws + WS_ET, ws + WS_SE, out, ws + WS_ACC);
  vq_final<<<1, 1, 0, stream>>>(ws, out);
}

// Round 6
// 327.931 us; speedup vs baseline: 3.9390x; 1.0128x over previous
//
#include <hip/hip_runtime.h>

// VQ-VAE quantize: input (16,64,64,64) f32, embeddings (64,2048) f32.
// Outputs concat in d_out: quantize_st[4194304], loss[1], embed_ind[65536] (as float).
//
// Correctness-critical (absmax 0.0 in rounds 1,2,4,5 — do not change arithmetic):
//   dist = fl( fl(sx - 2*dot) + se ),  dot = sequential-k FMA chain (k=0..63),
//   sx = numpy pairwise (8 accumulators + tree), se = sequential axis-0 sum,
//   argmin = first index of minimum (strict <, ascending j; wave slices ascending).
//
// Structure: 8 waves/block, wave w owns codes [w*256, w*256+256). Codes staged
// in 8-code chunks through WAVE-PRIVATE LDS (no barriers in main loop); all
// lanes read the same LDS address -> HW broadcast, conflict-free.
//
// Round-6: rounds 4-5 showed VGPR_Count=64 regardless of __launch_bounds__ —
// the scheduler targets achievable occupancy (4 blocks/CU by LDS) and spills x
// to AGPR, adding ~1.6x VALU issue (v_accvgpr_read per use). Fix:
//  (a) pad static LDS to ~56 KB -> 2 blocks/CU achievable -> 4 waves/SIMD
//      target -> 128-VGPR pressure budget;
//  (b) pin the 64 x scalars with an opaque asm identity so the loads cannot
//      be rematerialized into the loop.

#define HW     4096      // 64*64
#define CHW    262144    // 64*4096
#define NE     2048
#define OUT_Q  4194304   // NPIX*DIM
#define WS_ET  0         // ET[j][k]: 2048*64 floats
#define WS_SE  131072    // se[j]: 2048 floats
#define WS_ACC 133120    // loss accumulator: 1 float

__global__ __launch_bounds__(256) void vq_prep(const float* __restrict__ emb,
                                               float* __restrict__ ws) {
  int bid = blockIdx.x;
  if (bid < 512) {
    // transpose: ET[j*64+k] = emb[k*2048+j]; t = k*2048+j (coalesced read)
    int t = bid * 256 + threadIdx.x;
    int k = t >> 11;
    int j = t & 2047;
    ws[WS_ET + j * 64 + k] = emb[t];
  } else {
    // se[j] = sum_k fl(e_kj^2), sequential over k
    int j = (bid - 512) * 256 + threadIdx.x;
    float s = 0.0f;
    for (int k = 0; k < 64; ++k) {
      float e = emb[k * NE + j];
      s = __fadd_rn(s, __fmul_rn(e, e));
    }
    ws[WS_SE + j] = s;
    if (j == 0) ws[WS_ACC] = 0.0f;
  }
}

#define SQ(v) __fmul_rn(v, v)
// x as 64 named scalars (x<k>_<i>, k=0..15, i=0..3)
#define XDECL(k) \
  float x##k##_0 = xp[(4*k+0)*HW], x##k##_1 = xp[(4*k+1)*HW], \
        x##k##_2 = xp[(4*k+2)*HW], x##k##_3 = xp[(4*k+3)*HW];
// opaque identity: kills rematerialization of the x loads (forces VGPR residency)
#define XPIN(k) \
  asm volatile("" : "+v"(x##k##_0), "+v"(x##k##_1), "+v"(x##k##_2), "+v"(x##k##_3));
// two interleaved sequential-k FMA chains (independent ILP, per-chain order
// identical to rounds 1-5: k ascending, components 0,1,2,3)
#define DOTK(k) { \
  float4 ea = e0[k], eb = e1[k]; \
  d0 = __fmaf_rn(x##k##_0, ea.x, d0); d1 = __fmaf_rn(x##k##_0, eb.x, d1); \
  d0 = __fmaf_rn(x##k##_1, ea.y, d0); d1 = __fmaf_rn(x##k##_1, eb.y, d1); \
  d0 = __fmaf_rn(x##k##_2, ea.z, d0); d1 = __fmaf_rn(x##k##_2, eb.z, d1); \
  d0 = __fmaf_rn(x##k##_3, ea.w, d0); d1 = __fmaf_rn(x##k##_3, eb.w, d1); }
#define DOTALL() \
  DOTK(0) DOTK(1) DOTK(2) DOTK(3) DOTK(4) DOTK(5) DOTK(6) DOTK(7) \
  DOTK(8) DOTK(9) DOTK(10) DOTK(11) DOTK(12) DOTK(13) DOTK(14) DOTK(15)
// sx pairwise block: r0..r7 += squares of the 8 elements of (a,b) pair-chunks
#define SXB(a, b) \
  r0 = __fadd_rn(r0, SQ(a##_0)); r1 = __fadd_rn(r1, SQ(a##_1)); \
  r2 = __fadd_rn(r2, SQ(a##_2)); r3 = __fadd_rn(r3, SQ(a##_3)); \
  r4 = __fadd_rn(r4, SQ(b##_0)); r5 = __fadd_rn(r5, SQ(b##_1)); \
  r6 = __fadd_rn(r6, SQ(b##_2)); r7 = __fadd_rn(r7, SQ(b##_3));
// process the 8-code chunk currently in this wave's LDS buffer
#define CHUNK_BODY(jb_) { \
  const int jb = (jb_); \
  _Pragma("unroll") \
  for (int jl = 0; jl < 8; jl += 2) { \
    const float4* e0 = reinterpret_cast<const float4*>(&lds_e[wv][jl][0]); \
    const float4* e1 = reinterpret_cast<const float4*>(&lds_e[wv][jl + 1][0]); \
    float d0 = 0.0f, d1 = 0.0f; \
    DOTALL() \
    int j = jb + jl; \
    float dist0 = __fadd_rn(__fsub_rn(sx, __fmul_rn(2.0f, d0)), se[j]); \
    float dist1 = __fadd_rn(__fsub_rn(sx, __fmul_rn(2.0f, d1)), se[j + 1]); \
    if (dist0 < best) { best = dist0; bi = j; } \
    if (dist1 < best) { best = dist1; bi = j + 1; } \
  } }

__global__ __launch_bounds__(512, 1) void vq_main(const float* __restrict__ inp,
                                                  const float* __restrict__ et,
                                                  const float* __restrict__ se,
                                                  float* __restrict__ out,
                                                  float* __restrict__ loss_acc) {
  __shared__ float lds_e[8][8][64];   // 16 KB: per-wave 8-code chunk buffer
  __shared__ float rv[8][64];
  __shared__ int   ri[8][64];
  __shared__ float ls[8];
  // occupancy governor: pads static LDS to ~56 KB so the compiler's achievable
  // occupancy (and thus its register-pressure target) is 2 blocks/CU = 4
  // waves/SIMD = 128 VGPR. Referenced under a runtime-unprovable branch only.
  __shared__ float occ_pad[9088];

  const int tid  = threadIdx.x;
  const int lane = tid & 63;
  const int wv   = tid >> 6;                    // wave id = code-slice 0..7
  const int n    = blockIdx.x * 64 + lane;      // pixel id (same set for all waves)
  const int b    = n >> 12;
  const int rem  = n & 4095;                    // block never straddles b
  const float* xp = inp + (size_t)b * CHW + rem;

  // x in 64 named scalar registers (statically indexed only)
  XDECL(0)  XDECL(1)  XDECL(2)  XDECL(3)
  XDECL(4)  XDECL(5)  XDECL(6)  XDECL(7)
  XDECL(8)  XDECL(9)  XDECL(10) XDECL(11)
  XDECL(12) XDECL(13) XDECL(14) XDECL(15)

  // sx: numpy pairwise (8 accumulators over 8-element chunks, then tree) —
  // same accumulation order as rounds 1-5
  float r0 = SQ(x0_0), r1 = SQ(x0_1), r2 = SQ(x0_2), r3 = SQ(x0_3);
  float r4 = SQ(x1_0), r5 = SQ(x1_1), r6 = SQ(x1_2), r7 = SQ(x1_3);
  SXB(x2, x3)   SXB(x4, x5)   SXB(x6, x7)   SXB(x8, x9)
  SXB(x10, x11) SXB(x12, x13) SXB(x14, x15)
  const float sx =
      __fadd_rn(__fadd_rn(__fadd_rn(r0, r1), __fadd_rn(r2, r3)),
                __fadd_rn(__fadd_rn(r4, r5), __fadd_rn(r6, r7)));

  // pin x into VGPRs (opaque redefinition: loads above can't be remat'ed)
  XPIN(0)  XPIN(1)  XPIN(2)  XPIN(3)
  XPIN(4)  XPIN(5)  XPIN(6)  XPIN(7)
  XPIN(8)  XPIN(9)  XPIN(10) XPIN(11)
  XPIN(12) XPIN(13) XPIN(14) XPIN(15)

  // keep occ_pad allocated: grid is 1024, branch is never taken, but the
  // compiler cannot prove blockIdx.x's range.
  if (blockIdx.x == 0x7fffffff) occ_pad[tid] = sx;

  // wave-private staging: slice base for this wave (256 codes = 64 KB)
  const float4* ET4 = reinterpret_cast<const float4*>(et + wv * 256 * 64);
  float4* L4 = reinterpret_cast<float4*>(&lds_e[wv][0][0]);
  const int j0 = wv * 256;

  float best = 3.402823466e38f;
  int   bi   = 0;

  // prefetch chunk 0 into registers
  float4 p0 = ET4[lane], p1 = ET4[lane + 64];

#pragma unroll 1
  for (int c = 0; c < 31; ++c) {                // chunks 0..30 (8 codes each)
    // issue next-chunk loads early (T14): latency hides under this chunk's FMAs
    const float4* src = ET4 + (c + 1) * 128;
    float4 n0 = src[lane], n1 = src[lane + 64];

    // write current chunk to wave-private LDS (DS in-order: reads below see it)
    L4[lane] = p0;
    L4[lane + 64] = p1;

    CHUNK_BODY(j0 + c * 8)
    p0 = n0; p1 = n1;
  }
  // final chunk 31 (no prefetch)
  L4[lane] = p0;
  L4[lane + 64] = p1;
  CHUNK_BODY(j0 + 31 * 8)

  rv[wv][lane] = best;
  ri[wv][lane] = bi;
  __syncthreads();

  // merge across 8 waves (slices ascending in j -> strict < keeps lowest j)
  float bv  = rv[0][lane];
  int   bix = ri[0][lane];
#pragma unroll
  for (int s = 1; s < 8; ++s) {
    float v = rv[s][lane];
    if (v < bv) { bv = v; bix = ri[s][lane]; }
  }

  // epilogue: pixel = lane, wave wv writes channels [wv*8, wv*8+8)
  const float4* qr = reinterpret_cast<const float4*>(et + (size_t)bix * 64);
  float4 qa = qr[2 * wv], qb = qr[2 * wv + 1];
  float q[8] = {qa.x, qa.y, qa.z, qa.w, qb.x, qb.y, qb.z, qb.w};
  float* op = out + (size_t)b * CHW + rem;
  float lsum = 0.0f;
#pragma unroll
  for (int i = 0; i < 8; ++i) {
    int c = wv * 8 + i;
    float xv = xp[c * HW];                 // L1-hot re-read (avoids dynamic x-reg index)
    float d  = __fsub_rn(q[i], xv);
    op[c * HW] = __fadd_rn(xv, d);         // x + (q - x)
    lsum = __fadd_rn(lsum, __fmul_rn(d, d));
  }
  if (wv == 0) out[OUT_Q + 1 + n] = (float)bix;

  // loss: wave shfl reduce -> per-wave slot -> one atomic per block
#pragma unroll
  for (int off = 32; off > 0; off >>= 1)
    lsum = __fadd_rn(lsum, __shfl_xor(lsum, off, 64));
  if (lane == 0) ls[wv] = lsum;
  __syncthreads();
  if (tid == 0) {
    float s = ls[0];
#pragma unroll
    for (int w = 1; w < 8; ++w) s = __fadd_rn(s, ls[w]);
    atomicAdd(loss_acc, s);
  }
}

__global__ void vq_final(const float* __restrict__ ws, float* __restrict__ out) {
  float m = ws[WS_ACC] / 4194304.0f;              // exact pow2 divide
  out[OUT_Q] = __fadd_rn(m, __fmul_rn(0.25f, m)); // mean + 0.25*mean
}

extern "C" void kernel_launch(void* const* d_in, const int* in_sizes, int n_in,
                              void* d_out, int out_size, void* d_ws, size_t ws_size,
                              hipStream_t stream) {
  const float* inp = (const float*)d_in[0];
  const float* emb = (const float*)d_in[1];
  float* out = (float*)d_out;
  float* ws  = (float*)d_ws;

  vq_prep<<<520, 256, 0, stream>>>(emb, ws);
  vq_main<<<1024, 512, 0, stream>>>(inp, ws + WS_ET, ws + WS_SE, out, ws + WS_ACC);
  vq_final<<<1, 1, 0, stream>>>(ws, out);
}